// Round 2
// baseline (3168.108 us; speedup 1.0000x reference)
//
#include <hip/hip_runtime.h>
#include <hip/hip_bf16.h>
#include <stdint.h>

// Problem dims (fixed by the reference)
constexpr int cL = 6, cT = 128, cB = 256, cD = 512, cH = 8, cF = 2048, cS = 64;
constexpr int cM = cT * cB;  // 32768 token rows

typedef __bf16 bf16_t;
typedef __bf16 bf16x8 __attribute__((ext_vector_type(8)));
typedef __bf16 bf16x4 __attribute__((ext_vector_type(4)));
typedef float f32x4 __attribute__((ext_vector_type(4)));

// ---------------------------------------------------------------- cast f32->bf16
__global__ __launch_bounds__(256) void cast_kernel(const float* __restrict__ in,
                                                   bf16_t* __restrict__ out, int n) {
  int i = (blockIdx.x * 256 + threadIdx.x) * 4;
  if (i >= n) return;
  float4 v = *(const float4*)(in + i);
  bf16x4 o;
  o[0] = (bf16_t)v.x; o[1] = (bf16_t)v.y; o[2] = (bf16_t)v.z; o[3] = (bf16_t)v.w;
  *(bf16x4*)(out + i) = o;
}

// ---------------------------------------------------------------- bf16 GEMM (B^T)
// C[m,n] = sum_k A[m,k] * Bw[n,k] + bias[n], optional ReLU.
// R5 structure:
//  (1) XCD-chunked bijective blockIdx swizzle (T1) — R4: FETCH 67.6->24.7 MB.
//  (2) Triple-buffered LDS ring + COUNTED vmcnt (T4, m218): stage tile t+2
//      while computing tile t; main-loop wait is vmcnt(8) (loads of t+1,t+2
//      stay in flight across the barrier). R4's double-buffer drained
//      vmcnt(0) every K-step -> each iteration ate a full memory latency
//      (MfmaUtil 11%, hbm 7%, latency-bound). Depth-2 covers ~2 iterations
//      (~800 cyc) >= HBM latency. Drain-to-0 only in the 2-iter epilogue.
//  Rule #18 fencing: every wait is {asm vmcnt; s_barrier; sched_barrier(0)}.
__global__ __launch_bounds__(256) void gemm_bt_kernel(
    const bf16_t* __restrict__ A, const bf16_t* __restrict__ Bw,
    const float* __restrict__ bias, float* __restrict__ Cf, bf16_t* __restrict__ Cb,
    int K, int N, int relu) {
  __shared__ __align__(16) bf16_t As0[128 * 32];
  __shared__ __align__(16) bf16_t Bs0[128 * 32];
  __shared__ __align__(16) bf16_t As1[128 * 32];
  __shared__ __align__(16) bf16_t Bs1[128 * 32];
  __shared__ __align__(16) bf16_t As2[128 * 32];
  __shared__ __align__(16) bf16_t Bs2[128 * 32];
  const int tid = threadIdx.x;
  // (1) XCD-chunked swizzle (bijective when nwg % 8 == 0; all our grids are).
  int bx, by;
  {
    const unsigned gx = gridDim.x;
    const unsigned d = blockIdx.x + gx * blockIdx.y;
    const unsigned nwg = gx * gridDim.y;
    unsigned w = d;
    if ((nwg & 7u) == 0u) w = (d & 7u) * (nwg >> 3) + (d >> 3);
    bx = (int)(w % gx);
    by = (int)(w / gx);
  }
  const size_t m0 = (size_t)by * 128;
  const size_t n0 = (size_t)bx * 128;
  const int lane = tid & 63;
  const int wv = tid >> 6;
  const int wm = (wv >> 1) * 64;   // wave 2x2 grid, each 64x64
  const int wn = (wv & 1) * 64;
  const int sr = tid >> 2;         // staging row 0..63
  const int sk = (tid & 3) * 8;    // staging k element offset
  const bf16_t* gA1 = A + (m0 + sr) * K + sk;
  const bf16_t* gA2 = A + (m0 + 64 + sr) * K + sk;
  const bf16_t* gB1 = Bw + (n0 + sr) * K + sk;
  const bf16_t* gB2 = Bw + (n0 + 64 + sr) * K + sk;
  f32x4 acc[4][4];
  const f32x4 zero = {0.f, 0.f, 0.f, 0.f};
#pragma unroll
  for (int i = 0; i < 4; i++)
#pragma unroll
    for (int j = 0; j < 4; j++) acc[i][j] = zero;
  const int fr = lane & 15;
  const int kq = (lane >> 4) * 8;

  auto stage = [&](bf16_t* Ad, bf16_t* Bd, int k0) {
    __builtin_amdgcn_global_load_lds(
        (__attribute__((address_space(1))) void*)(gA1 + k0),
        (__attribute__((address_space(3))) void*)(Ad + tid * 8), 16, 0, 0);
    __builtin_amdgcn_global_load_lds(
        (__attribute__((address_space(1))) void*)(gA2 + k0),
        (__attribute__((address_space(3))) void*)(Ad + 2048 + tid * 8), 16, 0, 0);
    __builtin_amdgcn_global_load_lds(
        (__attribute__((address_space(1))) void*)(gB1 + k0),
        (__attribute__((address_space(3))) void*)(Bd + tid * 8), 16, 0, 0);
    __builtin_amdgcn_global_load_lds(
        (__attribute__((address_space(1))) void*)(gB2 + k0),
        (__attribute__((address_space(3))) void*)(Bd + 2048 + tid * 8), 16, 0, 0);
  };
  auto compute = [&](const bf16_t* As_, const bf16_t* Bs_) {
    bf16x8 af[4], bfr[4];
#pragma unroll
    for (int i = 0; i < 4; i++)
      af[i] = *(const bf16x8*)(As_ + (wm + i * 16 + fr) * 32 + kq);
#pragma unroll
    for (int i = 0; i < 4; i++)
      bfr[i] = *(const bf16x8*)(Bs_ + (wn + i * 16 + fr) * 32 + kq);
#pragma unroll
    for (int i = 0; i < 4; i++)
#pragma unroll
      for (int j = 0; j < 4; j++)
        acc[i][j] = __builtin_amdgcn_mfma_f32_16x16x32_bf16(af[i], bfr[j], acc[i][j], 0, 0, 0);
  };

  const int nt = K >> 5;  // K-tiles of 32 (16 for K=512, 64 for K=2048)
  bf16_t *pa0 = As0, *pb0 = Bs0;
  bf16_t *pa1 = As1, *pb1 = Bs1;
  bf16_t *pa2 = As2, *pb2 = Bs2;
  // prologue: tiles 0,1 in flight (8 loads outstanding)
  stage(pa0, pb0, 0);
  stage(pa1, pb1, 32);
  int ks = 64;
  for (int t = 0; t < nt; ++t) {
    if (t + 2 < nt) {
      stage(pa2, pb2, ks);  // tile t+2 -> 12 loads outstanding max
      ks += 32;
      asm volatile("s_waitcnt vmcnt(8)" ::: "memory");  // tile t landed; t+1,t+2 in flight
    } else if (t + 2 == nt) {
      asm volatile("s_waitcnt vmcnt(4)" ::: "memory");  // tile t landed; t+1 in flight
    } else {
      asm volatile("s_waitcnt vmcnt(0)" ::: "memory");  // last tile
    }
    __builtin_amdgcn_s_barrier();
    __builtin_amdgcn_sched_barrier(0);
    compute(pa0, pb0);
    __builtin_amdgcn_s_barrier();   // all waves done reading pa0 before it's restaged
    __builtin_amdgcn_sched_barrier(0);
    bf16_t* ta = pa0; pa0 = pa1; pa1 = pa2; pa2 = ta;
    bf16_t* tb = pb0; pb0 = pb1; pb1 = pb2; pb2 = tb;
  }

  const int row0 = wm + (lane >> 4) * 4;
  const int col0 = wn + fr;
#pragma unroll
  for (int j = 0; j < 4; j++) {
    const size_t n = n0 + col0 + j * 16;
    const float bv = bias[n];
#pragma unroll
    for (int i = 0; i < 4; i++) {
#pragma unroll
      for (int r = 0; r < 4; r++) {
        const size_t m = m0 + row0 + i * 16 + r;
        float v = acc[i][j][r] + bv;
        if (relu) v = fmaxf(v, 0.f);
        const size_t off = m * (size_t)N + n;
        if (Cf) Cf[off] = v;
        if (Cb) Cb[off] = (bf16_t)v;
      }
    }
  }
}

// ---------------------------------------------------------------- fused attention
// block = (h, t): scores over c=128 feats, softmax over the 256 b's, p = s*t,
// msg = p @ mw[h]^T + mb (MFMA), wm = relu(wt * msg)  [t-major, col h*64+u].
__global__ __launch_bounds__(256) void attn_kernel(
    const bf16_t* __restrict__ s, const bf16_t* __restrict__ t,
    const float* __restrict__ aw, const float* __restrict__ ab,
    const float* __restrict__ mw, const float* __restrict__ mb,
    bf16_t* __restrict__ wm) {
  constexpr int P = cS + 8;  // pad 64->72 to break 128B row stride (bank conflicts)
  __shared__ __align__(16) bf16_t p[cB][P];
  __shared__ __align__(16) bf16_t w[cS][P];
  __shared__ float score[cB];
  __shared__ float wt[cB];
  __shared__ float red[8];
  const int h = blockIdx.x;
  const int tt = blockIdx.y;
  const int tid = threadIdx.x;
  const int lane = tid & 63;
  const int wv = tid >> 6;
  // stage W_h (64x64 fp32 -> bf16 LDS)
  {
    const int u = tid >> 2;
    const int c16 = (tid & 3) * 16;
    const float* wr = mw + ((size_t)h * cS + u) * cS + c16;
#pragma unroll
    for (int q = 0; q < 2; q++) {
      float4 a = *(const float4*)(wr + q * 8);
      float4 bq = *(const float4*)(wr + q * 8 + 4);
      bf16x8 o;
      o[0] = (bf16_t)a.x; o[1] = (bf16_t)a.y; o[2] = (bf16_t)a.z; o[3] = (bf16_t)a.w;
      o[4] = (bf16_t)bq.x; o[5] = (bf16_t)bq.y; o[6] = (bf16_t)bq.z; o[7] = (bf16_t)bq.w;
      *(bf16x8*)(&w[u][c16 + q * 8]) = o;
    }
  }
  // load s,t head slices, compute p (bf16 LDS) + per-row score partials
  const int col8 = (tid & 7) * 8;
  const float* aws = aw + (size_t)h * 2 * cS;
  const float* awt = aws + cS;
#pragma unroll
  for (int r8 = 0; r8 < 8; r8++) {
    const int row = (tid >> 3) + r8 * 32;  // b index
    const size_t g = ((size_t)tt * cB + row) * cD + h * cS + col8;
    bf16x8 sv = *(const bf16x8*)(s + g);
    bf16x8 tv = *(const bf16x8*)(t + g);
    bf16x8 pv;
    float sc = 0.f;
#pragma unroll
    for (int i = 0; i < 8; i++) {
      float sf = (float)sv[i], tf = (float)tv[i];
      pv[i] = (bf16_t)(sf * tf);
      sc += sf * aws[col8 + i] + tf * awt[col8 + i];
    }
    *(bf16x8*)(&p[row][col8]) = pv;
    sc += __shfl_xor(sc, 1);
    sc += __shfl_xor(sc, 2);
    sc += __shfl_xor(sc, 4);
    if ((tid & 7) == 0) score[row] = sc;
  }
  __syncthreads();
  // softmax over the 256 b's
  {
    float v = score[tid];
    float m = v;
#pragma unroll
    for (int o = 32; o; o >>= 1) m = fmaxf(m, __shfl_xor(m, o));
    if (lane == 0) red[wv] = m;
    __syncthreads();
    const float mx = fmaxf(fmaxf(red[0], red[1]), fmaxf(red[2], red[3]));
    const float e = __expf(v - mx);
    float sm = e;
#pragma unroll
    for (int o = 32; o; o >>= 1) sm += __shfl_xor(sm, o);
    if (lane == 0) red[4 + wv] = sm;
    __syncthreads();
    const float tot = red[4] + red[5] + red[6] + red[7];
    wt[tid] = e / tot;
  }
  __syncthreads();
  // MFMA: wave wv handles rows wv*64..wv*64+63; out 64x64
  const int rbase = wv * 64;
  const int fr = lane & 15;
  const int kq = (lane >> 4) * 8;
  f32x4 acc[4][4];
  const f32x4 zero = {0.f, 0.f, 0.f, 0.f};
#pragma unroll
  for (int i = 0; i < 4; i++)
#pragma unroll
    for (int j = 0; j < 4; j++) acc[i][j] = zero;
#pragma unroll
  for (int k0 = 0; k0 < cS; k0 += 32) {
    bf16x8 af[4], bfr[4];
#pragma unroll
    for (int i = 0; i < 4; i++)
      af[i] = *(const bf16x8*)(&p[rbase + i * 16 + fr][k0 + kq]);
#pragma unroll
    for (int j = 0; j < 4; j++)
      bfr[j] = *(const bf16x8*)(&w[j * 16 + fr][k0 + kq]);
#pragma unroll
    for (int i = 0; i < 4; i++)
#pragma unroll
      for (int j = 0; j < 4; j++)
        acc[i][j] = __builtin_amdgcn_mfma_f32_16x16x32_bf16(af[i], bfr[j], acc[i][j], 0, 0, 0);
  }
  // epilogue: msg + bias, * wt, relu, store wm t-major
  const int row0 = (lane >> 4) * 4;
#pragma unroll
  for (int j = 0; j < 4; j++) {
    const int col = j * 16 + fr;            // u within head
    const float mbv = mb[h * cS + col];
#pragma unroll
    for (int i = 0; i < 4; i++) {
#pragma unroll
      for (int r = 0; r < 4; r++) {
        const int brow = rbase + i * 16 + row0 + r;
        float v = (acc[i][j][r] + mbv) * wt[brow];
        v = fmaxf(v, 0.f);
        wm[((size_t)tt * cB + brow) * cD + h * cS + col] = (bf16_t)v;
      }
    }
  }
}

// ---------------------------------------------------------------- add + layernorm
// rid (b-major) = rid0 + blockIdx.x; b = rid>>7, t = rid&127.
// Residual: inaF (fp32) or inaB (bf16), layout per a_tmajor.
// Addend: inbB (bf16, FULL buffer, layout per b_tmajor) or inbF (fp32, chunk-local
// b-major rows). Outputs optional fp32/bf16 with layout flags.
// In-place inaF==outF safe (row fully read before write, one wave per row).
__global__ __launch_bounds__(64) void ln_kernel(
    const float* __restrict__ inaF, const bf16_t* __restrict__ inaB, int a_tmajor,
    const float* __restrict__ inbF, const bf16_t* __restrict__ inbB, int b_tmajor,
    const float* __restrict__ gam, const float* __restrict__ bet,
    float* __restrict__ outF, int oF_tmajor, bf16_t* __restrict__ outB, int oB_tmajor,
    int rid0) {
  const int local = blockIdx.x;
  const int rid = rid0 + local;
  const int b = rid >> 7;
  const int t = rid & (cT - 1);
  const size_t tmaj = ((size_t)t * cB + b) * cD;
  const size_t bmaj = (size_t)rid * cD;
  const int d0 = threadIdx.x * 8;
  float v[8];
  if (inbB) {
    bf16x8 a = *(const bf16x8*)(inbB + (b_tmajor ? tmaj : bmaj) + d0);
#pragma unroll
    for (int i = 0; i < 8; i++) v[i] = (float)a[i];
  } else {
    const float4* pb = (const float4*)(inbF + (size_t)local * cD + d0);
    float4 b0 = pb[0], b1 = pb[1];
    v[0] = b0.x; v[1] = b0.y; v[2] = b0.z; v[3] = b0.w;
    v[4] = b1.x; v[5] = b1.y; v[6] = b1.z; v[7] = b1.w;
  }
  const size_t aoff = (a_tmajor ? tmaj : bmaj) + d0;
  if (inaF) {
    const float4* pa = (const float4*)(inaF + aoff);
    float4 a0 = pa[0], a1 = pa[1];
    v[0] += a0.x; v[1] += a0.y; v[2] += a0.z; v[3] += a0.w;
    v[4] += a1.x; v[5] += a1.y; v[6] += a1.z; v[7] += a1.w;
  } else {
    bf16x8 a = *(const bf16x8*)(inaB + aoff);
#pragma unroll
    for (int i = 0; i < 8; i++) v[i] += (float)a[i];
  }
  float sm = 0.f, sq = 0.f;
#pragma unroll
  for (int i = 0; i < 8; i++) { sm += v[i]; sq += v[i] * v[i]; }
#pragma unroll
  for (int o = 32; o; o >>= 1) { sm += __shfl_xor(sm, o); sq += __shfl_xor(sq, o); }
  const float mean = sm * (1.f / cD);
  const float var = sq * (1.f / cD) - mean * mean;
  const float rs = rsqrtf(var + 1e-5f);
  const float4 g0 = *(const float4*)(gam + d0);
  const float4 g1 = *(const float4*)(gam + d0 + 4);
  const float4 e0 = *(const float4*)(bet + d0);
  const float4 e1 = *(const float4*)(bet + d0 + 4);
  float o8[8];
  o8[0] = (v[0] - mean) * rs * g0.x + e0.x;
  o8[1] = (v[1] - mean) * rs * g0.y + e0.y;
  o8[2] = (v[2] - mean) * rs * g0.z + e0.z;
  o8[3] = (v[3] - mean) * rs * g0.w + e0.w;
  o8[4] = (v[4] - mean) * rs * g1.x + e1.x;
  o8[5] = (v[5] - mean) * rs * g1.y + e1.y;
  o8[6] = (v[6] - mean) * rs * g1.z + e1.z;
  o8[7] = (v[7] - mean) * rs * g1.w + e1.w;
  if (outF) {
    const size_t ooff = (oF_tmajor ? tmaj : bmaj) + d0;
    *(float4*)(outF + ooff) = make_float4(o8[0], o8[1], o8[2], o8[3]);
    *(float4*)(outF + ooff + 4) = make_float4(o8[4], o8[5], o8[6], o8[7]);
  }
  if (outB) {
    bf16x8 ob;
#pragma unroll
    for (int i = 0; i < 8; i++) ob[i] = (bf16_t)o8[i];
    *(bf16x8*)(outB + (oB_tmajor ? tmaj : bmaj) + d0) = ob;
  }
}

// ---------------------------------------------------------------- host
extern "C" void kernel_launch(void* const* d_in, const int* in_sizes, int n_in,
                              void* d_out, int out_size, void* d_ws, size_t ws_size,
                              hipStream_t stream) {
  (void)in_sizes; (void)n_in; (void)out_size;
  const float* src        = (const float*)d_in[0];
  const float* srcc       = (const float*)d_in[1];
  const float* spatio_w   = (const float*)d_in[2];
  const float* spatio_b   = (const float*)d_in[3];
  const float* temporal_w = (const float*)d_in[4];
  const float* temporal_b = (const float*)d_in[5];
  const float* attn_w     = (const float*)d_in[6];
  const float* attn_b     = (const float*)d_in[7];
  const float* msg_w      = (const float*)d_in[8];
  const float* msg_b      = (const float*)d_in[9];
  const float* agg_w      = (const float*)d_in[10];
  const float* agg_b      = (const float*)d_in[11];
  const float* lin1_w     = (const float*)d_in[12];
  const float* lin1_b     = (const float*)d_in[13];
  const float* lin2_w     = (const float*)d_in[14];
  const float* lin2_b     = (const float*)d_in[15];
  const float* ln1_g      = (const float*)d_in[16];
  const float* ln1_bb     = (const float*)d_in[17];
  const float* ln2_g      = (const float*)d_in[18];
  const float* ln2_bb     = (const float*)d_in[19];

  size_t off = 0;
  auto alloc = [&](size_t nbytes) -> void* {
    void* p = (char*)d_ws + off;
    off += (nbytes + 255) & ~(size_t)255;
    return p;
  };
  const size_t nTok = (size_t)cM;
  const size_t actB = nTok * cD * sizeof(bf16_t);  // 33.5 MB

  // Fixed (~202 MB)
  bf16_t* sw_bf   = (bf16_t*)alloc((size_t)cL * cD * cD * 2);
  bf16_t* tw_bf   = (bf16_t*)alloc((size_t)cL * cD * cD * 2);
  bf16_t* gw_bf   = (bf16_t*)alloc((size_t)cL * cD * cD * 2);
  bf16_t* w1_bf   = (bf16_t*)alloc((size_t)cL * cF * cD * 2);
  bf16_t* w2_bf   = (bf16_t*)alloc((size_t)cL * cD * cF * 2);
  bf16_t* srcc_bf = (bf16_t*)alloc(actB);
  bf16_t* cur_bf  = (bf16_t*)alloc(actB);   // layer input, bf16 t-major
  bf16_t* s_bf    = (bf16_t*)alloc(actB);   // s (t-major), then x (b-major)
  bf16_t* t_bf    = (bf16_t*)alloc(actB);   // t (t-major), then y (bf16 b-major)
  bf16_t* wmx_bf  = (bf16_t*)alloc(actB);   // wm (t-major)
  const size_t fixed_end = off;

  // Tiers: fp32 residual (precision) + FFN chunk Mc. S hosts aggB (phase 1,
  // 33.5 MB) then h1 (phase 2). Full-M h1 = 134 MB.
  const size_t residBytes = nTok * cD * 4;  // 67 MB
  const size_t slack = 1 << 20;
  size_t avail = (ws_size > fixed_end + slack) ? (ws_size - fixed_end - slack) : 0;
  auto sBytes = [&](int Mc) {
    size_t h1 = (size_t)Mc * cF * 2;
    return h1 > actB ? h1 : actB;
  };
  bool useResid; int Mc;
  if      (avail >= residBytes + sBytes(cM))    { useResid = true;  Mc = cM; }
  else if (avail >= residBytes + sBytes(16384)) { useResid = true;  Mc = 16384; }
  else if (avail >= sBytes(cM))                 { useResid = false; Mc = cM; }
  else if (avail >= sBytes(16384))              { useResid = false; Mc = 16384; }
  else                                          { useResid = false; Mc = 8192; }
  float*  resid = useResid ? (float*)alloc(residBytes) : nullptr;  // fp32 b-major
  void*   S     = alloc(sBytes(Mc));
  bf16_t* aggB  = (bf16_t*)S;       // agg, bf16 t-major full-M (phase 1)
  bf16_t* h1_bf = (bf16_t*)S;       // FFN hidden (phase 2; aggB dead)
  const int nCh = cM / Mc;

  auto cast = [&](const float* i, bf16_t* o, size_t n) {
    cast_kernel<<<dim3((unsigned)((n / 4 + 255) / 256)), dim3(256), 0, stream>>>(i, o, (int)n);
  };
  cast(spatio_w, sw_bf, (size_t)cL * cD * cD);
  cast(temporal_w, tw_bf, (size_t)cL * cD * cD);
  cast(agg_w, gw_bf, (size_t)cL * cD * cD);
  cast(lin1_w, w1_bf, (size_t)cL * cF * cD);
  cast(lin2_w, w2_bf, (size_t)cL * cD * cF);
  cast(srcc, srcc_bf, nTok * cD);
  cast(src, cur_bf, nTok * cD);

  const dim3 blk(256);
  for (int l = 0; l < cL; l++) {
    const bf16_t* swl = sw_bf + (size_t)l * cD * cD;
    const bf16_t* twl = tw_bf + (size_t)l * cD * cD;
    const bf16_t* gwl = gw_bf + (size_t)l * cD * cD;
    const bf16_t* w1l = w1_bf + (size_t)l * cF * cD;
    const bf16_t* w2l = w2_bf + (size_t)l * cD * cF;

    // s/t projections (t-major)
    gemm_bt_kernel<<<dim3(4, cM / 128), blk, 0, stream>>>(srcc_bf, swl, spatio_b + l * cD,
                                                          nullptr, s_bf, cD, cD, 1);
    gemm_bt_kernel<<<dim3(4, cM / 128), blk, 0, stream>>>(cur_bf, twl, temporal_b + l * cD,
                                                          nullptr, t_bf, cD, cD, 1);
    // fused scores+softmax+message -> wm (t-major)
    attn_kernel<<<dim3(cH, cT), blk, 0, stream>>>(
        s_bf, t_bf, attn_w + (size_t)l * cH * 2 * cS, attn_b + l * cH,
        msg_w + (size_t)l * cH * cS * cS, msg_b + l * cH * cS, wmx_bf);
    // agg (full-M, bf16 t-major out)
    gemm_bt_kernel<<<dim3(4, cM / 128), blk, 0, stream>>>(wmx_bf, gwl, agg_b + l * cD,
                                                          nullptr, aggB, cD, cD, 0);
    // ln1 full-M: x = LN(residual + agg); x -> resid (fp32 b-major) + s_bf (bf16 b-major)
    {
      const float* iaF = nullptr; const bf16_t* iaB = nullptr; int a_t = 0;
      if (useResid) { if (l == 0) { iaF = src; a_t = 1; } else { iaF = resid; } }
      else          { iaB = cur_bf; a_t = 1; }
      ln_kernel<<<dim3(cM), dim3(64), 0, stream>>>(
          iaF, iaB, a_t, nullptr, aggB, 1, ln1_g + l * cD, ln1_bb + l * cD,
          resid, 0, s_bf, 0, 0);
    }
    // FFN: lin1 x->h1, lin2 h1->y (bf16, b-major, into dead t_bf)
    for (int c = 0; c < nCh; c++) {
      const int r0 = c * Mc;
      gemm_bt_kernel<<<dim3(cF / 128, Mc / 128), blk, 0, stream>>>(
          s_bf + (size_t)r0 * cD, w1l, lin1_b + l * cF, nullptr, h1_bf, cD, cF, 1);
      gemm_bt_kernel<<<dim3(4, Mc / 128), blk, 0, stream>>>(
          h1_bf, w2l, lin2_b + l * cD, nullptr, t_bf + (size_t)r0 * cD, cF, cD, 0);
    }
    // ln2 full-M: out = LN(x + y); next-layer resid + cur_bf (t-major)
    {
      const float* iaF = useResid ? resid : nullptr;
      const bf16_t* iaB = useResid ? nullptr : s_bf;
      float* oF; int oFt;
      if (l == cL - 1) { oF = (float*)d_out; oFt = 1; }
      else if (useResid) { oF = resid; oFt = 0; }
      else { oF = nullptr; oFt = 0; }
      ln_kernel<<<dim3(cM), dim3(64), 0, stream>>>(
          iaF, iaB, 0, nullptr, t_bf, 0, ln2_g + l * cD, ln2_bb + l * cD,
          oF, oFt, (l == cL - 1) ? nullptr : cur_bf, 1, 0);
    }
  }
}

// Round 3
// 2218.624 us; speedup vs baseline: 1.4280x; 1.4280x over previous
//
#include <hip/hip_runtime.h>
#include <hip/hip_bf16.h>
#include <stdint.h>

// Problem dims (fixed by the reference)
constexpr int cL = 6, cT = 128, cB = 256, cD = 512, cH = 8, cF = 2048, cS = 64;
constexpr int cM = cT * cB;  // 32768 token rows

typedef __bf16 bf16_t;
typedef __bf16 bf16x8 __attribute__((ext_vector_type(8)));
typedef __bf16 bf16x4 __attribute__((ext_vector_type(4)));
typedef float f32x4 __attribute__((ext_vector_type(4)));

// ---------------------------------------------------------------- cast f32->bf16
__global__ __launch_bounds__(256) void cast_kernel(const float* __restrict__ in,
                                                   bf16_t* __restrict__ out, int n) {
  int i = (blockIdx.x * 256 + threadIdx.x) * 4;
  if (i >= n) return;
  float4 v = *(const float4*)(in + i);
  bf16x4 o;
  o[0] = (bf16_t)v.x; o[1] = (bf16_t)v.y; o[2] = (bf16_t)v.z; o[3] = (bf16_t)v.w;
  *(bf16x4*)(out + i) = o;
}

// ---------------------------------------------------------------- bf16 GEMM (B^T)
// C[m,n] = sum_k A[m,k] * Bw[n,k] + bias[n], optional ReLU. bf16 out only.
// R6 structure (R4/R5 post-mortem: pipeline depth = null on 2-phase; per-step
// overhead is the floor):
//  (1) XCD-chunked bijective swizzle (T1) — kept (FETCH 67.6->24.7 MB).
//  (2) BK=64: halves barrier count; 32 MFMA + 16 ds_read_b128 per wave/step.
//      dbuf = 64 KB LDS -> 2 blocks/CU.
//  (3) LDS slot-swizzle (rule #21 both-sides): physical 16B-slot
//      s = q ^ (row&7). Applied on the GLOBAL source address at stage
//      (LDS dest stays wave-linear as global_load_lds requires) and on the
//      ds_read address. 128B rows unswizzled would be 16-way bank-serialized.
//  (4) Epilogue via LDS: C-tile bf16 staged in the (dead) K-loop LDS,
//      written with 8x b128 coalesced stores/thread instead of 64 scalar 2B.
//  (5) Dual-operand dispatch: blockIdx.z picks {A,Bw,bias,C} set (merges the
//      s/t projections into one launch).
__global__ __launch_bounds__(256) void gemm_bt_kernel(
    const bf16_t* __restrict__ A0, const bf16_t* __restrict__ Bw0,
    const float* __restrict__ bias0, bf16_t* __restrict__ C0,
    const bf16_t* __restrict__ A1, const bf16_t* __restrict__ Bw1,
    const float* __restrict__ bias1, bf16_t* __restrict__ C1,
    int K, int N, int relu) {
  __shared__ __align__(16) bf16_t lds[4 * 128 * 64];  // 64 KB
  bf16_t* const As0 = lds;
  bf16_t* const Bs0 = lds + 8192;
  bf16_t* const As1 = lds + 16384;
  bf16_t* const Bs1 = lds + 24576;
  const int tid = threadIdx.x;
  const bf16_t* A  = (blockIdx.z == 0) ? A0 : A1;
  const bf16_t* Bw = (blockIdx.z == 0) ? Bw0 : Bw1;
  const float* bias = (blockIdx.z == 0) ? bias0 : bias1;
  bf16_t* C = (blockIdx.z == 0) ? C0 : C1;
  // (1) XCD-chunked swizzle within this z-plane (bijective when nwg%8==0).
  int bx, by;
  {
    const unsigned gx = gridDim.x;
    const unsigned d = blockIdx.x + gx * blockIdx.y;
    const unsigned nwg = gx * gridDim.y;
    unsigned w = d;
    if ((nwg & 7u) == 0u) w = (d & 7u) * (nwg >> 3) + (d >> 3);
    bx = (int)(w % gx);
    by = (int)(w / gx);
  }
  const size_t m0 = (size_t)by * 128;
  const size_t n0 = (size_t)bx * 128;
  const int lane = tid & 63;
  const int wv = tid >> 6;
  const int wm = (wv >> 1) * 64;   // wave 2x2 grid, each 64x64
  const int wn = (wv & 1) * 64;
  // staging mapping: thread covers row srow(+i*32), physical 16B slot sslot.
  // Source uses swizzled slot ssw so that read-side slot q lives at q^(row&7).
  const int srow = tid >> 3;          // 0..31
  const int sslot = tid & 7;          // 0..7
  const int ssw = sslot ^ (srow & 7); // swizzled source slot
  const bf16_t* gA = A + (m0 + srow) * K + ssw * 8;
  const bf16_t* gB = Bw + (n0 + srow) * K + ssw * 8;
  f32x4 acc[4][4];
  const f32x4 zero = {0.f, 0.f, 0.f, 0.f};
#pragma unroll
  for (int i = 0; i < 4; i++)
#pragma unroll
    for (int j = 0; j < 4; j++) acc[i][j] = zero;
  const int fr = lane & 15;
  const int kq = (lane >> 4) * 8;       // 0,8,16,24 within a 32-K chunk
  const int swr = fr & 7;               // row&7 for all fragment rows

  auto stage = [&](bf16_t* Ad, bf16_t* Bd, int k0) {
#pragma unroll
    for (int i = 0; i < 4; i++)
      __builtin_amdgcn_global_load_lds(
          (__attribute__((address_space(1))) void*)(gA + (size_t)i * 32 * K + k0),
          (__attribute__((address_space(3))) void*)(Ad + i * 2048 + tid * 8), 16, 0, 0);
#pragma unroll
    for (int i = 0; i < 4; i++)
      __builtin_amdgcn_global_load_lds(
          (__attribute__((address_space(1))) void*)(gB + (size_t)i * 32 * K + k0),
          (__attribute__((address_space(3))) void*)(Bd + i * 2048 + tid * 8), 16, 0, 0);
  };
  auto compute = [&](const bf16_t* As_, const bf16_t* Bs_) {
#pragma unroll
    for (int kk = 0; kk < 2; kk++) {
      const int ls = kk * 4 + (kq >> 3);        // logical 16B slot 0..7
      const int sc = (ls ^ swr) * 8;            // swizzled element col
      bf16x8 af[4], bfr[4];
#pragma unroll
      for (int i = 0; i < 4; i++)
        af[i] = *(const bf16x8*)(As_ + (wm + i * 16 + fr) * 64 + sc);
#pragma unroll
      for (int j = 0; j < 4; j++)
        bfr[j] = *(const bf16x8*)(Bs_ + (wn + j * 16 + fr) * 64 + sc);
#pragma unroll
      for (int i = 0; i < 4; i++)
#pragma unroll
        for (int j = 0; j < 4; j++)
          acc[i][j] = __builtin_amdgcn_mfma_f32_16x16x32_bf16(af[i], bfr[j], acc[i][j], 0, 0, 0);
    }
  };

  const int nt = K >> 6;  // K-tiles of 64 (8 for K=512, 32 for K=2048)
  bf16_t *ca = As0, *cb = Bs0, *na = As1, *nb = Bs1;
  stage(ca, cb, 0);
  int pk = 64;
  for (int t = 0; t < nt; ++t) {
    if (t + 1 < nt) {
      stage(na, nb, pk);   // prefetch next tile (8 loads; 16 outstanding)
      pk += 64;
      asm volatile("s_waitcnt vmcnt(8)" ::: "memory");  // current tile landed
    } else {
      asm volatile("s_waitcnt vmcnt(0)" ::: "memory");
    }
    __builtin_amdgcn_s_barrier();
    __builtin_amdgcn_sched_barrier(0);
    compute(ca, cb);
    __builtin_amdgcn_s_barrier();   // all waves done reading before restage
    __builtin_amdgcn_sched_barrier(0);
    bf16_t* t0 = ca; ca = na; na = t0;
    bf16_t* t1 = cb; cb = nb; nb = t1;
  }

  // ---- epilogue: bias+relu -> LDS C-tile -> coalesced b128 stores.
  // LDS is dead (vmcnt drained at last iter, post-compute barrier passed).
  constexpr int CP = 136;  // 128 + 8 pad: row stride 272B (16B-aligned, bank-spread)
  bf16_t* const ct = lds;
  const int row0 = wm + (lane >> 4) * 4;
#pragma unroll
  for (int j = 0; j < 4; j++) {
    const int col = wn + j * 16 + fr;
    const float bv = bias[n0 + col];
#pragma unroll
    for (int i = 0; i < 4; i++) {
#pragma unroll
      for (int r = 0; r < 4; r++) {
        float v = acc[i][j][r] + bv;
        if (relu) v = fmaxf(v, 0.f);
        ct[(row0 + i * 16 + r) * CP + col] = (bf16_t)v;
      }
    }
  }
  __syncthreads();
  const int erc = (tid & 15) * 8;   // element col
  const int err = tid >> 4;         // row within 16-row pass
#pragma unroll
  for (int p = 0; p < 8; p++) {
    const int row = p * 16 + err;
    bf16x8 vv = *(const bf16x8*)(ct + row * CP + erc);
    *(bf16x8*)(C + (m0 + row) * (size_t)N + n0 + erc) = vv;
  }
}

// ---------------------------------------------------------------- fused attention
// block = (h, t): scores over c=128 feats, softmax over the 256 b's, p = s*t,
// msg = p @ mw[h]^T + mb (MFMA), wm = relu(wt * msg)  [t-major, col h*64+u].
__global__ __launch_bounds__(256) void attn_kernel(
    const bf16_t* __restrict__ s, const bf16_t* __restrict__ t,
    const float* __restrict__ aw, const float* __restrict__ ab,
    const float* __restrict__ mw, const float* __restrict__ mb,
    bf16_t* __restrict__ wm) {
  constexpr int P = cS + 8;  // pad 64->72 to break 128B row stride (bank conflicts)
  __shared__ __align__(16) bf16_t p[cB][P];
  __shared__ __align__(16) bf16_t w[cS][P];
  __shared__ float score[cB];
  __shared__ float wt[cB];
  __shared__ float red[8];
  const int h = blockIdx.x;
  const int tt = blockIdx.y;
  const int tid = threadIdx.x;
  const int lane = tid & 63;
  const int wv = tid >> 6;
  // stage W_h (64x64 fp32 -> bf16 LDS)
  {
    const int u = tid >> 2;
    const int c16 = (tid & 3) * 16;
    const float* wr = mw + ((size_t)h * cS + u) * cS + c16;
#pragma unroll
    for (int q = 0; q < 2; q++) {
      float4 a = *(const float4*)(wr + q * 8);
      float4 bq = *(const float4*)(wr + q * 8 + 4);
      bf16x8 o;
      o[0] = (bf16_t)a.x; o[1] = (bf16_t)a.y; o[2] = (bf16_t)a.z; o[3] = (bf16_t)a.w;
      o[4] = (bf16_t)bq.x; o[5] = (bf16_t)bq.y; o[6] = (bf16_t)bq.z; o[7] = (bf16_t)bq.w;
      *(bf16x8*)(&w[u][c16 + q * 8]) = o;
    }
  }
  // load s,t head slices, compute p (bf16 LDS) + per-row score partials
  const int col8 = (tid & 7) * 8;
  const float* aws = aw + (size_t)h * 2 * cS;
  const float* awt = aws + cS;
#pragma unroll
  for (int r8 = 0; r8 < 8; r8++) {
    const int row = (tid >> 3) + r8 * 32;  // b index
    const size_t g = ((size_t)tt * cB + row) * cD + h * cS + col8;
    bf16x8 sv = *(const bf16x8*)(s + g);
    bf16x8 tv = *(const bf16x8*)(t + g);
    bf16x8 pv;
    float sc = 0.f;
#pragma unroll
    for (int i = 0; i < 8; i++) {
      float sf = (float)sv[i], tf = (float)tv[i];
      pv[i] = (bf16_t)(sf * tf);
      sc += sf * aws[col8 + i] + tf * awt[col8 + i];
    }
    *(bf16x8*)(&p[row][col8]) = pv;
    sc += __shfl_xor(sc, 1);
    sc += __shfl_xor(sc, 2);
    sc += __shfl_xor(sc, 4);
    if ((tid & 7) == 0) score[row] = sc;
  }
  __syncthreads();
  // softmax over the 256 b's
  {
    float v = score[tid];
    float m = v;
#pragma unroll
    for (int o = 32; o; o >>= 1) m = fmaxf(m, __shfl_xor(m, o));
    if (lane == 0) red[wv] = m;
    __syncthreads();
    const float mx = fmaxf(fmaxf(red[0], red[1]), fmaxf(red[2], red[3]));
    const float e = __expf(v - mx);
    float sm = e;
#pragma unroll
    for (int o = 32; o; o >>= 1) sm += __shfl_xor(sm, o);
    if (lane == 0) red[4 + wv] = sm;
    __syncthreads();
    const float tot = red[4] + red[5] + red[6] + red[7];
    wt[tid] = e / tot;
  }
  __syncthreads();
  // MFMA: wave wv handles rows wv*64..wv*64+63; out 64x64
  const int rbase = wv * 64;
  const int fr = lane & 15;
  const int kq = (lane >> 4) * 8;
  f32x4 acc[4][4];
  const f32x4 zero = {0.f, 0.f, 0.f, 0.f};
#pragma unroll
  for (int i = 0; i < 4; i++)
#pragma unroll
    for (int j = 0; j < 4; j++) acc[i][j] = zero;
#pragma unroll
  for (int k0 = 0; k0 < cS; k0 += 32) {
    bf16x8 af[4], bfr[4];
#pragma unroll
    for (int i = 0; i < 4; i++)
      af[i] = *(const bf16x8*)(&p[rbase + i * 16 + fr][k0 + kq]);
#pragma unroll
    for (int j = 0; j < 4; j++)
      bfr[j] = *(const bf16x8*)(&w[j * 16 + fr][k0 + kq]);
#pragma unroll
    for (int i = 0; i < 4; i++)
#pragma unroll
      for (int j = 0; j < 4; j++)
        acc[i][j] = __builtin_amdgcn_mfma_f32_16x16x32_bf16(af[i], bfr[j], acc[i][j], 0, 0, 0);
  }
  // epilogue: msg + bias, * wt, relu, store wm t-major
  const int row0 = (lane >> 4) * 4;
#pragma unroll
  for (int j = 0; j < 4; j++) {
    const int col = j * 16 + fr;            // u within head
    const float mbv = mb[h * cS + col];
#pragma unroll
    for (int i = 0; i < 4; i++) {
#pragma unroll
      for (int r = 0; r < 4; r++) {
        const int brow = rbase + i * 16 + row0 + r;
        float v = (acc[i][j][r] + mbv) * wt[brow];
        v = fmaxf(v, 0.f);
        wm[((size_t)tt * cB + brow) * cD + h * cS + col] = (bf16_t)v;
      }
    }
  }
}

// ---------------------------------------------------------------- add + layernorm
// rid (b-major) = rid0 + blockIdx.x; b = rid>>7, t = rid&127.
// Residual: inaF (fp32) or inaB (bf16), layout per a_tmajor.
// Addend: inbB (bf16, FULL buffer, layout per b_tmajor) or inbF (fp32, chunk-local
// b-major rows). Outputs optional fp32/bf16 with layout flags.
// In-place inaF==outF safe (row fully read before write, one wave per row).
__global__ __launch_bounds__(64) void ln_kernel(
    const float* __restrict__ inaF, const bf16_t* __restrict__ inaB, int a_tmajor,
    const float* __restrict__ inbF, const bf16_t* __restrict__ inbB, int b_tmajor,
    const float* __restrict__ gam, const float* __restrict__ bet,
    float* __restrict__ outF, int oF_tmajor, bf16_t* __restrict__ outB, int oB_tmajor,
    int rid0) {
  const int local = blockIdx.x;
  const int rid = rid0 + local;
  const int b = rid >> 7;
  const int t = rid & (cT - 1);
  const size_t tmaj = ((size_t)t * cB + b) * cD;
  const size_t bmaj = (size_t)rid * cD;
  const int d0 = threadIdx.x * 8;
  float v[8];
  if (inbB) {
    bf16x8 a = *(const bf16x8*)(inbB + (b_tmajor ? tmaj : bmaj) + d0);
#pragma unroll
    for (int i = 0; i < 8; i++) v[i] = (float)a[i];
  } else {
    const float4* pb = (const float4*)(inbF + (size_t)local * cD + d0);
    float4 b0 = pb[0], b1 = pb[1];
    v[0] = b0.x; v[1] = b0.y; v[2] = b0.z; v[3] = b0.w;
    v[4] = b1.x; v[5] = b1.y; v[6] = b1.z; v[7] = b1.w;
  }
  const size_t aoff = (a_tmajor ? tmaj : bmaj) + d0;
  if (inaF) {
    const float4* pa = (const float4*)(inaF + aoff);
    float4 a0 = pa[0], a1 = pa[1];
    v[0] += a0.x; v[1] += a0.y; v[2] += a0.z; v[3] += a0.w;
    v[4] += a1.x; v[5] += a1.y; v[6] += a1.z; v[7] += a1.w;
  } else {
    bf16x8 a = *(const bf16x8*)(inaB + aoff);
#pragma unroll
    for (int i = 0; i < 8; i++) v[i] += (float)a[i];
  }
  float sm = 0.f, sq = 0.f;
#pragma unroll
  for (int i = 0; i < 8; i++) { sm += v[i]; sq += v[i] * v[i]; }
#pragma unroll
  for (int o = 32; o; o >>= 1) { sm += __shfl_xor(sm, o); sq += __shfl_xor(sq, o); }
  const float mean = sm * (1.f / cD);
  const float var = sq * (1.f / cD) - mean * mean;
  const float rs = rsqrtf(var + 1e-5f);
  const float4 g0 = *(const float4*)(gam + d0);
  const float4 g1 = *(const float4*)(gam + d0 + 4);
  const float4 e0 = *(const float4*)(bet + d0);
  const float4 e1 = *(const float4*)(bet + d0 + 4);
  float o8[8];
  o8[0] = (v[0] - mean) * rs * g0.x + e0.x;
  o8[1] = (v[1] - mean) * rs * g0.y + e0.y;
  o8[2] = (v[2] - mean) * rs * g0.z + e0.z;
  o8[3] = (v[3] - mean) * rs * g0.w + e0.w;
  o8[4] = (v[4] - mean) * rs * g1.x + e1.x;
  o8[5] = (v[5] - mean) * rs * g1.y + e1.y;
  o8[6] = (v[6] - mean) * rs * g1.z + e1.z;
  o8[7] = (v[7] - mean) * rs * g1.w + e1.w;
  if (outF) {
    const size_t ooff = (oF_tmajor ? tmaj : bmaj) + d0;
    *(float4*)(outF + ooff) = make_float4(o8[0], o8[1], o8[2], o8[3]);
    *(float4*)(outF + ooff + 4) = make_float4(o8[4], o8[5], o8[6], o8[7]);
  }
  if (outB) {
    bf16x8 ob;
#pragma unroll
    for (int i = 0; i < 8; i++) ob[i] = (bf16_t)o8[i];
    *(bf16x8*)(outB + (oB_tmajor ? tmaj : bmaj) + d0) = ob;
  }
}

// ---------------------------------------------------------------- host
extern "C" void kernel_launch(void* const* d_in, const int* in_sizes, int n_in,
                              void* d_out, int out_size, void* d_ws, size_t ws_size,
                              hipStream_t stream) {
  (void)in_sizes; (void)n_in; (void)out_size;
  const float* src        = (const float*)d_in[0];
  const float* srcc       = (const float*)d_in[1];
  const float* spatio_w   = (const float*)d_in[2];
  const float* spatio_b   = (const float*)d_in[3];
  const float* temporal_w = (const float*)d_in[4];
  const float* temporal_b = (const float*)d_in[5];
  const float* attn_w     = (const float*)d_in[6];
  const float* attn_b     = (const float*)d_in[7];
  const float* msg_w      = (const float*)d_in[8];
  const float* msg_b      = (const float*)d_in[9];
  const float* agg_w      = (const float*)d_in[10];
  const float* agg_b      = (const float*)d_in[11];
  const float* lin1_w     = (const float*)d_in[12];
  const float* lin1_b     = (const float*)d_in[13];
  const float* lin2_w     = (const float*)d_in[14];
  const float* lin2_b     = (const float*)d_in[15];
  const float* ln1_g      = (const float*)d_in[16];
  const float* ln1_bb     = (const float*)d_in[17];
  const float* ln2_g      = (const float*)d_in[18];
  const float* ln2_bb     = (const float*)d_in[19];

  size_t off = 0;
  auto alloc = [&](size_t nbytes) -> void* {
    void* p = (char*)d_ws + off;
    off += (nbytes + 255) & ~(size_t)255;
    return p;
  };
  const size_t nTok = (size_t)cM;
  const size_t actB = nTok * cD * sizeof(bf16_t);  // 33.5 MB

  // Fixed (~202 MB)
  bf16_t* sw_bf   = (bf16_t*)alloc((size_t)cL * cD * cD * 2);
  bf16_t* tw_bf   = (bf16_t*)alloc((size_t)cL * cD * cD * 2);
  bf16_t* gw_bf   = (bf16_t*)alloc((size_t)cL * cD * cD * 2);
  bf16_t* w1_bf   = (bf16_t*)alloc((size_t)cL * cF * cD * 2);
  bf16_t* w2_bf   = (bf16_t*)alloc((size_t)cL * cD * cF * 2);
  bf16_t* srcc_bf = (bf16_t*)alloc(actB);
  bf16_t* cur_bf  = (bf16_t*)alloc(actB);   // layer input, bf16 t-major
  bf16_t* s_bf    = (bf16_t*)alloc(actB);   // s (t-major), then x (b-major)
  bf16_t* t_bf    = (bf16_t*)alloc(actB);   // t (t-major), then y (bf16 b-major)
  bf16_t* wmx_bf  = (bf16_t*)alloc(actB);   // wm (t-major)
  const size_t fixed_end = off;

  // Tiers: fp32 residual (precision) + FFN chunk Mc. S hosts aggB (phase 1,
  // 33.5 MB) then h1 (phase 2). Full-M h1 = 134 MB.
  const size_t residBytes = nTok * cD * 4;  // 67 MB
  const size_t slack = 1 << 20;
  size_t avail = (ws_size > fixed_end + slack) ? (ws_size - fixed_end - slack) : 0;
  auto sBytes = [&](int Mc) {
    size_t h1 = (size_t)Mc * cF * 2;
    return h1 > actB ? h1 : actB;
  };
  bool useResid; int Mc;
  if      (avail >= residBytes + sBytes(cM))    { useResid = true;  Mc = cM; }
  else if (avail >= residBytes + sBytes(16384)) { useResid = true;  Mc = 16384; }
  else if (avail >= sBytes(cM))                 { useResid = false; Mc = cM; }
  else if (avail >= sBytes(16384))              { useResid = false; Mc = 16384; }
  else                                          { useResid = false; Mc = 8192; }
  float*  resid = useResid ? (float*)alloc(residBytes) : nullptr;  // fp32 b-major
  void*   S     = alloc(sBytes(Mc));
  bf16_t* aggB  = (bf16_t*)S;       // agg, bf16 t-major full-M (phase 1)
  bf16_t* h1_bf = (bf16_t*)S;       // FFN hidden (phase 2; aggB dead)
  const int nCh = cM / Mc;

  auto cast = [&](const float* i, bf16_t* o, size_t n) {
    cast_kernel<<<dim3((unsigned)((n / 4 + 255) / 256)), dim3(256), 0, stream>>>(i, o, (int)n);
  };
  cast(spatio_w, sw_bf, (size_t)cL * cD * cD);
  cast(temporal_w, tw_bf, (size_t)cL * cD * cD);
  cast(agg_w, gw_bf, (size_t)cL * cD * cD);
  cast(lin1_w, w1_bf, (size_t)cL * cF * cD);
  cast(lin2_w, w2_bf, (size_t)cL * cD * cF);
  cast(srcc, srcc_bf, nTok * cD);
  cast(src, cur_bf, nTok * cD);

  const dim3 blk(256);
  for (int l = 0; l < cL; l++) {
    const bf16_t* swl = sw_bf + (size_t)l * cD * cD;
    const bf16_t* twl = tw_bf + (size_t)l * cD * cD;
    const bf16_t* gwl = gw_bf + (size_t)l * cD * cD;
    const bf16_t* w1l = w1_bf + (size_t)l * cF * cD;
    const bf16_t* w2l = w2_bf + (size_t)l * cD * cF;

    // s/t projections (t-major), merged into one dispatch via blockIdx.z
    gemm_bt_kernel<<<dim3(4, cM / 128, 2), blk, 0, stream>>>(
        srcc_bf, swl, spatio_b + l * cD, s_bf,
        cur_bf, twl, temporal_b + l * cD, t_bf, cD, cD, 1);
    // fused scores+softmax+message -> wm (t-major)
    attn_kernel<<<dim3(cH, cT), blk, 0, stream>>>(
        s_bf, t_bf, attn_w + (size_t)l * cH * 2 * cS, attn_b + l * cH,
        msg_w + (size_t)l * cH * cS * cS, msg_b + l * cH * cS, wmx_bf);
    // agg (full-M, bf16 t-major out)
    gemm_bt_kernel<<<dim3(4, cM / 128, 1), blk, 0, stream>>>(
        wmx_bf, gwl, agg_b + l * cD, aggB,
        nullptr, nullptr, nullptr, nullptr, cD, cD, 0);
    // ln1 full-M: x = LN(residual + agg); x -> resid (fp32 b-major) + s_bf (bf16 b-major)
    {
      const float* iaF = nullptr; const bf16_t* iaB = nullptr; int a_t = 0;
      if (useResid) { if (l == 0) { iaF = src; a_t = 1; } else { iaF = resid; } }
      else          { iaB = cur_bf; a_t = 1; }
      ln_kernel<<<dim3(cM), dim3(64), 0, stream>>>(
          iaF, iaB, a_t, nullptr, aggB, 1, ln1_g + l * cD, ln1_bb + l * cD,
          resid, 0, s_bf, 0, 0);
    }
    // FFN: lin1 x->h1, lin2 h1->y (bf16, b-major, into dead t_bf)
    for (int c = 0; c < nCh; c++) {
      const int r0 = c * Mc;
      gemm_bt_kernel<<<dim3(cF / 128, Mc / 128, 1), blk, 0, stream>>>(
          s_bf + (size_t)r0 * cD, w1l, lin1_b + l * cF, h1_bf,
          nullptr, nullptr, nullptr, nullptr, cD, cF, 1);
      gemm_bt_kernel<<<dim3(4, Mc / 128, 1), blk, 0, stream>>>(
          h1_bf, w2l, lin2_b + l * cD, t_bf + (size_t)r0 * cD,
          nullptr, nullptr, nullptr, nullptr, cF, cD, 0);
    }
    // ln2 full-M: out = LN(x + y); next-layer resid + cur_bf (t-major)
    {
      const float* iaF = useResid ? resid : nullptr;
      const bf16_t* iaB = useResid ? nullptr : s_bf;
      float* oF; int oFt;
      if (l == cL - 1) { oF = (float*)d_out; oFt = 1; }
      else if (useResid) { oF = resid; oFt = 0; }
      else { oF = nullptr; oFt = 0; }
      ln_kernel<<<dim3(cM), dim3(64), 0, stream>>>(
          iaF, iaB, 0, nullptr, t_bf, 0, ln2_g + l * cD, ln2_bb + l * cD,
          oF, oFt, (l == cL - 1) ? nullptr : cur_bf, 1, 0);
    }
  }
}